// Round 2
// baseline (63.190 us; speedup 1.0000x reference)
//
#include <hip/hip_runtime.h>
#include <hip/hip_bf16.h>

// Problem constants
#define B_DIM   32768
#define A_DIM   64
#define L_DIM   1024          // K
#define N_COLS  128           // 2*A
#define KSTEPS  32            // K=32 per MFMA step

using bf16x8 = __attribute__((ext_vector_type(8))) __bf16;
using f32x4  = __attribute__((ext_vector_type(4))) float;

// ---------------------------------------------------------------------------
// Pre-kernel: convert W [128 x 1024] f32 -> bf16 in MFMA B-fragment order.
// Unit v (16B bf16x8): nl=v&15, sub=(v>>4)&3, cf=(v>>6)&7, ks=(v>>9)&31
//   holds Wm[n = cf*16+nl][k = ks*32 + sub*8 + i], i=0..7
// Main kernel reads unit (ks*8 + cf)*64 + lane  -> contiguous 1KB per wave-load.
// ---------------------------------------------------------------------------
__global__ __launch_bounds__(256)
void convert_w_kernel(const float* __restrict__ W, bf16x8* __restrict__ ws) {
    int v   = blockIdx.x * 256 + threadIdx.x;   // 0..16383
    int nl  = v & 15;
    int sub = (v >> 4) & 3;
    int cf  = (v >> 6) & 7;
    int ks  = (v >> 9) & 31;
    int n   = cf * 16 + nl;
    int k   = ks * 32 + sub * 8;
    const float4* wp = (const float4*)(W + (size_t)n * L_DIM + k);
    float4 w0 = wp[0];
    float4 w1 = wp[1];
    bf16x8 u;
    u[0] = (__bf16)w0.x; u[1] = (__bf16)w0.y;
    u[2] = (__bf16)w0.z; u[3] = (__bf16)w0.w;
    u[4] = (__bf16)w1.x; u[5] = (__bf16)w1.y;
    u[6] = (__bf16)w1.z; u[7] = (__bf16)w1.w;
    ws[v] = u;
}

// ---------------------------------------------------------------------------
// Main GEMM: no LDS, no barriers. Block = 4 waves covering 32 rows x 128 cols
// (wave = 16 rows x 64 cols; rowgrp = wave>>1, colgrp = wave&1).
// Grid = 1024 blocks -> 4 blocks/CU -> 16 waves/CU.
// ---------------------------------------------------------------------------
__global__ __launch_bounds__(256, 4)
void branched_policy_kernel(const float* __restrict__ F,
                            const bf16x8* __restrict__ Wf,
                            const float* __restrict__ bias,
                            float* __restrict__ out) {
    const int tid    = threadIdx.x;
    const int lane   = tid & 63;
    const int wave   = tid >> 6;
    const int rowgrp = wave >> 1;
    const int colgrp = wave & 1;
    const int lcol   = lane & 15;   // A row / B col within fragment
    const int lsub   = lane >> 4;   // k subgroup 0..3
    const int blk    = blockIdx.x;

    const int arow = blk * 32 + rowgrp * 16 + lcol;
    const float*  Fp = F + (size_t)arow * L_DIM + lsub * 8;
    const bf16x8* Bp = Wf + (size_t)colgrp * 4 * 64 + lane;

    f32x4 acc[4];
    #pragma unroll
    for (int c = 0; c < 4; ++c) acc[c] = (f32x4){0.f, 0.f, 0.f, 0.f};

    #pragma unroll 4
    for (int ks = 0; ks < KSTEPS; ++ks) {
        const float4* ap = (const float4*)(Fp + ks * 32);
        float4 a0 = ap[0];
        float4 a1 = ap[1];
        bf16x8 af;
        af[0] = (__bf16)a0.x; af[1] = (__bf16)a0.y;
        af[2] = (__bf16)a0.z; af[3] = (__bf16)a0.w;
        af[4] = (__bf16)a1.x; af[5] = (__bf16)a1.y;
        af[6] = (__bf16)a1.z; af[7] = (__bf16)a1.w;
        #pragma unroll
        for (int c = 0; c < 4; ++c) {
            bf16x8 bf = Bp[(size_t)(ks * 8 + c) * 64];   // 16B/lane, L2-hit
            acc[c] = __builtin_amdgcn_mfma_f32_16x16x32_bf16(af, bf, acc[c], 0, 0, 0);
        }
    }

    // Epilogue: bias + tanh + de-interleave (even n -> out0, odd n -> out1)
    const int orow0 = blk * 32 + rowgrp * 16 + lsub * 4;
    float* out0 = out;
    float* out1 = out + (size_t)B_DIM * A_DIM;
    #pragma unroll
    for (int c = 0; c < 4; ++c) {
        int   n  = (colgrp * 4 + c) * 16 + lcol;
        float bv = bias[n];
        float* obase = (n & 1) ? out1 : out0;
        int   aidx  = n >> 1;
        #pragma unroll
        for (int j = 0; j < 4; ++j) {
            float x = acc[c][j] + bv;
            // tanh(x) = 1 - 2/(exp(2x)+1); correct limits at +/-inf
            float e = __expf(2.0f * x);
            float t = 1.0f - 2.0f / (e + 1.0f);
            obase[(size_t)(orow0 + j) * A_DIM + aidx] = t;
        }
    }
}

// ---------------------------------------------------------------------------
// Fallback (v1, LDS-staging, proven correct) in case ws_size < 256 KB.
// ---------------------------------------------------------------------------
__global__ __launch_bounds__(256, 2)
void fallback_kernel(const float* __restrict__ F,
                     const float* __restrict__ W,
                     const float* __restrict__ bias,
                     float* __restrict__ out) {
    __shared__ bf16x8 ldsB[4096];
    const int tid  = threadIdx.x;
    const int lane = tid & 63;
    const int wave = tid >> 6;
    const int blk  = blockIdx.x;
    const int lcol = lane & 15;
    const int lsub = lane >> 4;
    const int arow = blk * 64 + wave * 16 + lcol;
    const float* Fp = F + (size_t)arow * L_DIM + lsub * 8;

    f32x4 acc[8];
    #pragma unroll
    for (int c = 0; c < 8; ++c) acc[c] = (f32x4){0.f, 0.f, 0.f, 0.f};

    for (int ch = 0; ch < 4; ++ch) {
        __syncthreads();
        #pragma unroll
        for (int i = 0; i < 16; ++i) {
            int v   = i * 256 + tid;
            int nl  = v & 15;
            int sub = (v >> 4) & 3;
            int c   = (v >> 6) & 7;
            int ks  = (v >> 9) & 7;
            int n   = c * 16 + nl;
            int k   = ch * 256 + ks * 32 + sub * 8;
            const float4* wp = (const float4*)(W + (size_t)n * L_DIM + k);
            float4 w0 = wp[0];
            float4 w1 = wp[1];
            bf16x8 u;
            u[0] = (__bf16)w0.x; u[1] = (__bf16)w0.y;
            u[2] = (__bf16)w0.z; u[3] = (__bf16)w0.w;
            u[4] = (__bf16)w1.x; u[5] = (__bf16)w1.y;
            u[6] = (__bf16)w1.z; u[7] = (__bf16)w1.w;
            ldsB[v] = u;
        }
        __syncthreads();
        #pragma unroll
        for (int ks = 0; ks < 8; ++ks) {
            const float4* ap = (const float4*)(Fp + ch * 256 + ks * 32);
            float4 a0 = ap[0];
            float4 a1 = ap[1];
            bf16x8 af;
            af[0] = (__bf16)a0.x; af[1] = (__bf16)a0.y;
            af[2] = (__bf16)a0.z; af[3] = (__bf16)a0.w;
            af[4] = (__bf16)a1.x; af[5] = (__bf16)a1.y;
            af[6] = (__bf16)a1.z; af[7] = (__bf16)a1.w;
            #pragma unroll
            for (int c = 0; c < 8; ++c) {
                bf16x8 bf = ldsB[(ks * 8 + c) * 64 + lane];
                acc[c] = __builtin_amdgcn_mfma_f32_16x16x32_bf16(af, bf, acc[c], 0, 0, 0);
            }
        }
    }

    const int orow0 = blk * 64 + wave * 16 + lsub * 4;
    float* out0 = out;
    float* out1 = out + (size_t)B_DIM * A_DIM;
    #pragma unroll
    for (int c = 0; c < 8; ++c) {
        int   n  = c * 16 + lcol;
        float bv = bias[n];
        float* obase = (n & 1) ? out1 : out0;
        int   aidx  = n >> 1;
        #pragma unroll
        for (int j = 0; j < 4; ++j) {
            float x = acc[c][j] + bv;
            float e = __expf(2.0f * x);
            float t = 1.0f - 2.0f / (e + 1.0f);
            obase[(size_t)(orow0 + j) * A_DIM + aidx] = t;
        }
    }
}

extern "C" void kernel_launch(void* const* d_in, const int* in_sizes, int n_in,
                              void* d_out, int out_size, void* d_ws, size_t ws_size,
                              hipStream_t stream) {
    const float* F    = (const float*)d_in[0];  // [32768, 1024] f32
    const float* W    = (const float*)d_in[1];  // [64, 2, 1024] f32
    const float* bias = (const float*)d_in[2];  // [64, 2] f32
    float* outp       = (float*)d_out;          // [2][32768, 64] f32

    const size_t ws_needed = (size_t)N_COLS * L_DIM * sizeof(__bf16);  // 256 KB

    if (ws_size >= ws_needed) {
        bf16x8* wf = (bf16x8*)d_ws;
        hipLaunchKernelGGL(convert_w_kernel, dim3(64), dim3(256), 0, stream, W, wf);
        hipLaunchKernelGGL(branched_policy_kernel, dim3(B_DIM / 32), dim3(256), 0, stream,
                           F, wf, bias, outp);
    } else {
        hipLaunchKernelGGL(fallback_kernel, dim3(B_DIM / 64), dim3(256), 0, stream,
                           F, W, bias, outp);
    }
}

// Round 3
// 36.098 us; speedup vs baseline: 1.7505x; 1.7505x over previous
//
#include <hip/hip_runtime.h>
#include <hip/hip_bf16.h>

// Problem constants
#define B_DIM   32768
#define A_DIM   64
#define L_DIM   1024          // K
#define N_COLS  128           // 2*A
#define R_TILES 8             // 16-row tiles per block
#define NBLK    256           // B_DIM / (R_TILES*16)

using bf16x8 = __attribute__((ext_vector_type(8))) __bf16;
using f32x4  = __attribute__((ext_vector_type(4))) float;

// ---------------------------------------------------------------------------
// Pre-kernel: convert W [128 x 1024] f32 -> bf16 in MFMA B-fragment order.
// Unit v: nl=v&15, sub=(v>>4)&3, cf=(v>>6)&7, ks=(v>>9)&31
//   holds Wm[n = cf*16+nl][k = ks*32 + sub*8 + i], i=0..7
// ---------------------------------------------------------------------------
__global__ __launch_bounds__(256)
void convert_w_kernel(const float* __restrict__ W, bf16x8* __restrict__ ws) {
    int v   = blockIdx.x * 256 + threadIdx.x;   // 0..16383
    int nl  = v & 15;
    int sub = (v >> 4) & 3;
    int cf  = (v >> 6) & 7;
    int ks  = (v >> 9) & 31;
    int n   = cf * 16 + nl;
    int k   = ks * 32 + sub * 8;
    const float4* wp = (const float4*)(W + (size_t)n * L_DIM + k);
    float4 w0 = wp[0];
    float4 w1 = wp[1];
    bf16x8 u;
    u[0] = (__bf16)w0.x; u[1] = (__bf16)w0.y;
    u[2] = (__bf16)w0.z; u[3] = (__bf16)w0.w;
    u[4] = (__bf16)w1.x; u[5] = (__bf16)w1.y;
    u[6] = (__bf16)w1.z; u[7] = (__bf16)w1.w;
    ws[v] = u;
}

__device__ __forceinline__ bf16x8 cvt8(float4 a, float4 b) {
    bf16x8 u;
    u[0] = (__bf16)a.x; u[1] = (__bf16)a.y; u[2] = (__bf16)a.z; u[3] = (__bf16)a.w;
    u[4] = (__bf16)b.x; u[5] = (__bf16)b.y; u[6] = (__bf16)b.z; u[7] = (__bf16)b.w;
    return u;
}

__device__ __forceinline__ void issue_tile(const float* fp, float4 S[4][2]) {
    #pragma unroll
    for (int i = 0; i < 4; ++i) {
        S[i][0] = *(const float4*)(fp + i * 256);
        S[i][1] = *(const float4*)(fp + i * 256 + 4);
    }
}

__device__ __forceinline__ void write_tile(char* lb, float4 S[4][2], int sr, int sc) {
    #pragma unroll
    for (int i = 0; i < 4; ++i) {
        int ks = i * 8 + (sc >> 2);
        int wb = (ks << 10) + ((sc & 3) << 8) + (sr << 4);
        wb ^= ((ks & 7) << 4);
        *(bf16x8*)(lb + wb) = cvt8(S[i][0], S[i][1]);
    }
}

// ---------------------------------------------------------------------------
// Main kernel: 512 threads = 8 waves. Wave w owns cols [16w, 16w+16), B for
// its cols x full K resident in 128 VGPRs. A staged per 16-row tile into
// LDS (bf16, fragment order, XOR-swizzled), double-buffered, depth-2
// register prefetch. Grid = 256 blocks = 1 block/CU, 128 rows each.
// ---------------------------------------------------------------------------
__global__ __launch_bounds__(512, 2)
void branched_policy_kernel(const float* __restrict__ F,
                            const bf16x8* __restrict__ Wf,
                            const float* __restrict__ bias,
                            float* __restrict__ out) {
    __shared__ bf16x8 ldsA[2][2048];   // 2 x 32 KB

    const int tid  = threadIdx.x;
    const int lane = tid & 63;
    const int wave = tid >> 6;        // col-frag 0..7
    const int blk  = blockIdx.x;
    const int lcol = lane & 15;       // A row within fragment
    const int lsub = lane >> 4;       // k subgroup 0..3

    // staging map: thread -> (row sr, 8-consecutive-k chunk at sc*8 per 256-k block)
    const int sr = tid >> 5;          // 0..15
    const int sc = tid & 31;          // 0..31
    const float* fbase = F + (size_t)(blk * 128 + sr) * L_DIM + sc * 8;

    float4 sA[4][2], sB[4][2];

    // depth-2 prefetch prologue
    issue_tile(fbase, sA);                          // tile 0
    issue_tile(fbase + 16 * L_DIM, sB);             // tile 1

    // B fragments: one-time load, stays in registers
    bf16x8 breg[32];
    #pragma unroll
    for (int ks = 0; ks < 32; ++ks)
        breg[ks] = Wf[(size_t)(ks * 8 + wave) * 64 + lane];

    const int   n  = wave * 16 + lcol;
    const float bv = bias[n];
    float* obase = ((n & 1) ? (out + (size_t)B_DIM * A_DIM) : out) + (n >> 1);

    write_tile((char*)&ldsA[0][0], sA, sr, sc);     // waits vmcnt for sA only
    __syncthreads();

    #pragma unroll
    for (int t = 0; t < R_TILES; ++t) {
        if (t + 2 < R_TILES)
            issue_tile(fbase + (size_t)(t + 2) * 16 * L_DIM,
                       ((t & 1) == 0) ? sA : sB);   // t static after unroll

        // ---- compute tile t ----
        f32x4 acc0 = (f32x4){0.f, 0.f, 0.f, 0.f};
        f32x4 acc1 = (f32x4){0.f, 0.f, 0.f, 0.f};
        const char* lb = (const char*)&ldsA[t & 1][0];
        #pragma unroll
        for (int ks = 0; ks < 32; ++ks) {
            int rb = (ks << 10) + (lsub << 8) + (lcol << 4);
            rb ^= ((ks & 7) << 4);
            bf16x8 af = *(const bf16x8*)(lb + rb);
            if (ks & 1)
                acc1 = __builtin_amdgcn_mfma_f32_16x16x32_bf16(af, breg[ks], acc1, 0, 0, 0);
            else
                acc0 = __builtin_amdgcn_mfma_f32_16x16x32_bf16(af, breg[ks], acc0, 0, 0, 0);
        }

        // ---- epilogue for tile t ----
        const int orow0 = blk * 128 + t * 16 + lsub * 4;
        #pragma unroll
        for (int j = 0; j < 4; ++j) {
            float x = acc0[j] + acc1[j] + bv;
            float e = __expf(2.0f * x);                 // tanh = 1 - 2/(e^2x+1)
            obase[(size_t)(orow0 + j) * A_DIM] = 1.0f - 2.0f / (e + 1.0f);
        }

        __syncthreads();
        if (t + 1 < R_TILES)
            write_tile((char*)&ldsA[(t + 1) & 1][0],
                       ((t & 1) == 0) ? sB : sA, sr, sc);
        __syncthreads();
    }
}

// ---------------------------------------------------------------------------
// Fallback (v1-style, self-contained) if ws is too small.
// ---------------------------------------------------------------------------
__global__ __launch_bounds__(256, 2)
void fallback_kernel(const float* __restrict__ F,
                     const float* __restrict__ W,
                     const float* __restrict__ bias,
                     float* __restrict__ out) {
    __shared__ bf16x8 ldsB[4096];
    const int tid  = threadIdx.x;
    const int lane = tid & 63;
    const int wave = tid >> 6;
    const int blk  = blockIdx.x;
    const int lcol = lane & 15;
    const int lsub = lane >> 4;
    const int arow = blk * 64 + wave * 16 + lcol;
    const float* Fp = F + (size_t)arow * L_DIM + lsub * 8;

    f32x4 acc[8];
    #pragma unroll
    for (int c = 0; c < 8; ++c) acc[c] = (f32x4){0.f, 0.f, 0.f, 0.f};

    for (int ch = 0; ch < 4; ++ch) {
        __syncthreads();
        #pragma unroll
        for (int i = 0; i < 16; ++i) {
            int v   = i * 256 + tid;
            int nl  = v & 15;
            int sub = (v >> 4) & 3;
            int c   = (v >> 6) & 7;
            int ks  = (v >> 9) & 7;
            int nn  = c * 16 + nl;
            int k   = ch * 256 + ks * 32 + sub * 8;
            const float4* wp = (const float4*)(W + (size_t)nn * L_DIM + k);
            ldsB[v] = cvt8(wp[0], wp[1]);
        }
        __syncthreads();
        #pragma unroll
        for (int ks = 0; ks < 8; ++ks) {
            const float4* ap = (const float4*)(Fp + ch * 256 + ks * 32);
            bf16x8 af = cvt8(ap[0], ap[1]);
            #pragma unroll
            for (int c = 0; c < 8; ++c) {
                bf16x8 bf = ldsB[(ks * 8 + c) * 64 + lane];
                acc[c] = __builtin_amdgcn_mfma_f32_16x16x32_bf16(af, bf, acc[c], 0, 0, 0);
            }
        }
    }

    const int orow0 = blk * 64 + wave * 16 + lsub * 4;
    float* out0 = out;
    float* out1 = out + (size_t)B_DIM * A_DIM;
    #pragma unroll
    for (int c = 0; c < 8; ++c) {
        int   nn = c * 16 + lcol;
        float bvv = bias[nn];
        float* ob = (nn & 1) ? out1 : out0;
        #pragma unroll
        for (int j = 0; j < 4; ++j) {
            float x = acc[c][j] + bvv;
            float e = __expf(2.0f * x);
            ob[(size_t)(orow0 + j) * A_DIM + (nn >> 1)] = 1.0f - 2.0f / (e + 1.0f);
        }
    }
}

extern "C" void kernel_launch(void* const* d_in, const int* in_sizes, int n_in,
                              void* d_out, int out_size, void* d_ws, size_t ws_size,
                              hipStream_t stream) {
    const float* F    = (const float*)d_in[0];  // [32768, 1024] f32
    const float* W    = (const float*)d_in[1];  // [64, 2, 1024] f32
    const float* bias = (const float*)d_in[2];  // [64, 2] f32
    float* outp       = (float*)d_out;          // [2][32768, 64] f32

    const size_t ws_needed = (size_t)N_COLS * L_DIM * sizeof(__bf16);  // 256 KB

    if (ws_size >= ws_needed) {
        bf16x8* wf = (bf16x8*)d_ws;
        hipLaunchKernelGGL(convert_w_kernel, dim3(64), dim3(256), 0, stream, W, wf);
        hipLaunchKernelGGL(branched_policy_kernel, dim3(NBLK), dim3(512), 0, stream,
                           F, wf, bias, outp);
    } else {
        hipLaunchKernelGGL(fallback_kernel, dim3(B_DIM / 64), dim3(256), 0, stream,
                           F, W, bias, outp);
    }
}

// Round 4
// 35.409 us; speedup vs baseline: 1.7846x; 1.0194x over previous
//
#include <hip/hip_runtime.h>
#include <hip/hip_bf16.h>

// Problem constants
#define B_DIM   32768
#define A_DIM   64
#define L_DIM   1024          // K
#define N_COLS  128           // 2*A
#define R_TILES 8             // 16-row tiles per block
#define NBLK    256           // B_DIM / (R_TILES*16) -> 1 block per CU

using bf16x8 = __attribute__((ext_vector_type(8))) __bf16;
using f32x4  = __attribute__((ext_vector_type(4))) float;

// ---------------------------------------------------------------------------
// Pre-kernel: convert W [128 x 1024] f32 -> bf16 in MFMA B-fragment order.
// Unit v: nl=v&15, sub=(v>>4)&3, cf=(v>>6)&7, ks=(v>>9)&31
//   holds Wm[n = cf*16+nl][k = ks*32 + sub*8 + i], i=0..7
// ---------------------------------------------------------------------------
__global__ __launch_bounds__(256)
void convert_w_kernel(const float* __restrict__ W, bf16x8* __restrict__ ws) {
    int v   = blockIdx.x * 256 + threadIdx.x;   // 0..16383
    int nl  = v & 15;
    int sub = (v >> 4) & 3;
    int cf  = (v >> 6) & 7;
    int ks  = (v >> 9) & 31;
    int n   = cf * 16 + nl;
    int k   = ks * 32 + sub * 8;
    const float4* wp = (const float4*)(W + (size_t)n * L_DIM + k);
    float4 w0 = wp[0];
    float4 w1 = wp[1];
    bf16x8 u;
    u[0] = (__bf16)w0.x; u[1] = (__bf16)w0.y;
    u[2] = (__bf16)w0.z; u[3] = (__bf16)w0.w;
    u[4] = (__bf16)w1.x; u[5] = (__bf16)w1.y;
    u[6] = (__bf16)w1.z; u[7] = (__bf16)w1.w;
    ws[v] = u;
}

__device__ __forceinline__ bf16x8 cvt8(float4 a, float4 b) {
    bf16x8 u;
    u[0] = (__bf16)a.x; u[1] = (__bf16)a.y; u[2] = (__bf16)a.z; u[3] = (__bf16)a.w;
    u[4] = (__bf16)b.x; u[5] = (__bf16)b.y; u[6] = (__bf16)b.z; u[7] = (__bf16)b.w;
    return u;
}

// ---------------------------------------------------------------------------
// Main kernel: 512 threads = 8 waves. Wave w owns cols [16w,16w+16); its B
// (16 cols x K=1024) lives in 128 registers, loaded once. A staged per
// 16-row tile into LDS as bf16 in EXACT fragment order:
//   unit u = ks*64 + lsub*16 + lcol  <->  A[row=lcol][k=ks*32+lsub*8 ..+8)
// LDS writes: thread tid writes units i*512+tid  (lane-contiguous, 0 confl)
// LDS reads:  wave reads units ks*64+lane        (lane-contiguous, 0 confl)
// The permutation lives on the GLOBAL side: thread tid fetches
//   F[blk*128 + t*16 + (tid&15)][ (i*8+wave)*32 + ((tid>>4)&3)*8 ..+8 )
// (16 rows x 128B contiguous per wave-instruction pair -> line-complete).
// One barrier per tile; depth-3 register prefetch keeps HBM streaming.
// ---------------------------------------------------------------------------
__global__ __launch_bounds__(512, 2)
void branched_policy_kernel(const float* __restrict__ F,
                            const bf16x8* __restrict__ Wf,
                            const float* __restrict__ bias,
                            float* __restrict__ out) {
    __shared__ bf16x8 ldsA[2][2048];   // 2 x 32 KB

    const int tid  = threadIdx.x;
    const int lane = tid & 63;
    const int wave = tid >> 6;        // col-frag 0..7
    const int blk  = blockIdx.x;
    const int lcol = lane & 15;       // fragment row (compute) / col (B)
    const int lsub = lane >> 4;       // k subgroup 0..3

    // staging: global source for owned units i*512+tid
    const int g_row = tid & 15;
    const int g_sub = (tid >> 4) & 3;
    const float* fb = F + (size_t)(blk * 128 + g_row) * L_DIM
                        + wave * 32 + g_sub * 8;

    float4 sA[4][2], sB[4][2];

    // ---- prologue: issue tiles 0,1 ----
    #pragma unroll
    for (int i = 0; i < 4; ++i) {
        sA[i][0] = *(const float4*)(fb + i * 256);
        sA[i][1] = *(const float4*)(fb + i * 256 + 4);
    }
    #pragma unroll
    for (int i = 0; i < 4; ++i) {
        sB[i][0] = *(const float4*)(fb + 16 * L_DIM + i * 256);
        sB[i][1] = *(const float4*)(fb + 16 * L_DIM + i * 256 + 4);
    }

    // B fragments: one-time load, stays resident (VGPR/AGPR)
    bf16x8 breg[32];
    #pragma unroll
    for (int ks = 0; ks < 32; ++ks)
        breg[ks] = Wf[(size_t)(ks * 8 + wave) * 64 + lane];

    const int   n  = wave * 16 + lcol;
    const float bv = bias[n];
    float* obase = ((n & 1) ? (out + (size_t)B_DIM * A_DIM) : out) + (n >> 1);

    // write tile0 -> lds[0]; refill sA with tile2
    #pragma unroll
    for (int i = 0; i < 4; ++i)
        ldsA[0][i * 512 + tid] = cvt8(sA[i][0], sA[i][1]);
    #pragma unroll
    for (int i = 0; i < 4; ++i) {
        sA[i][0] = *(const float4*)(fb + 2 * 16 * L_DIM + i * 256);
        sA[i][1] = *(const float4*)(fb + 2 * 16 * L_DIM + i * 256 + 4);
    }
    __syncthreads();

    #pragma unroll
    for (int t = 0; t < R_TILES; ++t) {
        // invariant: lds[t&1]=tile t; s_next holds tile t+1 (arrived);
        //            other reg buffer holds tile t+2 (in flight)
        float4 (*s_next)[2] = (t & 1) ? sA : sB;

        if (t + 1 < R_TILES) {
            #pragma unroll
            for (int i = 0; i < 4; ++i)
                ldsA[(t + 1) & 1][i * 512 + tid] =
                    cvt8(s_next[i][0], s_next[i][1]);
        }
        if (t + 3 < R_TILES) {
            const float* fp = fb + (size_t)(t + 3) * 16 * L_DIM;
            #pragma unroll
            for (int i = 0; i < 4; ++i) {
                s_next[i][0] = *(const float4*)(fp + i * 256);
                s_next[i][1] = *(const float4*)(fp + i * 256 + 4);
            }
        }

        // ---- compute tile t ----
        f32x4 acc0 = (f32x4){0.f, 0.f, 0.f, 0.f};
        f32x4 acc1 = (f32x4){0.f, 0.f, 0.f, 0.f};
        const bf16x8* lb = &ldsA[t & 1][0];
        #pragma unroll
        for (int ks = 0; ks < 32; ++ks) {
            bf16x8 af = lb[ks * 64 + lane];
            if (ks & 1)
                acc1 = __builtin_amdgcn_mfma_f32_16x16x32_bf16(af, breg[ks], acc1, 0, 0, 0);
            else
                acc0 = __builtin_amdgcn_mfma_f32_16x16x32_bf16(af, breg[ks], acc0, 0, 0, 0);
        }

        // ---- epilogue tile t ----
        const int orow0 = blk * 128 + t * 16 + lsub * 4;
        #pragma unroll
        for (int j = 0; j < 4; ++j) {
            float x = acc0[j] + acc1[j] + bv;
            float e = __expf(2.0f * x);                 // tanh = 1 - 2/(e^2x+1)
            obase[(size_t)(orow0 + j) * A_DIM] = 1.0f - 2.0f / (e + 1.0f);
        }

        __syncthreads();
    }
}

// ---------------------------------------------------------------------------
// Fallback (v1-style, self-contained) if ws is too small.
// ---------------------------------------------------------------------------
__global__ __launch_bounds__(256, 2)
void fallback_kernel(const float* __restrict__ F,
                     const float* __restrict__ W,
                     const float* __restrict__ bias,
                     float* __restrict__ out) {
    __shared__ bf16x8 ldsB[4096];
    const int tid  = threadIdx.x;
    const int lane = tid & 63;
    const int wave = tid >> 6;
    const int blk  = blockIdx.x;
    const int lcol = lane & 15;
    const int lsub = lane >> 4;
    const int arow = blk * 64 + wave * 16 + lcol;
    const float* Fp = F + (size_t)arow * L_DIM + lsub * 8;

    f32x4 acc[8];
    #pragma unroll
    for (int c = 0; c < 8; ++c) acc[c] = (f32x4){0.f, 0.f, 0.f, 0.f};

    for (int ch = 0; ch < 4; ++ch) {
        __syncthreads();
        #pragma unroll
        for (int i = 0; i < 16; ++i) {
            int v   = i * 256 + tid;
            int nl  = v & 15;
            int sub = (v >> 4) & 3;
            int c   = (v >> 6) & 7;
            int ks  = (v >> 9) & 7;
            int nn  = c * 16 + nl;
            int k   = ch * 256 + ks * 32 + sub * 8;
            const float4* wp = (const float4*)(W + (size_t)nn * L_DIM + k);
            ldsB[v] = cvt8(wp[0], wp[1]);
        }
        __syncthreads();
        #pragma unroll
        for (int ks = 0; ks < 8; ++ks) {
            const float4* ap = (const float4*)(Fp + ch * 256 + ks * 32);
            bf16x8 af = cvt8(ap[0], ap[1]);
            #pragma unroll
            for (int c = 0; c < 8; ++c) {
                bf16x8 bf = ldsB[(ks * 8 + c) * 64 + lane];
                acc[c] = __builtin_amdgcn_mfma_f32_16x16x32_bf16(af, bf, acc[c], 0, 0, 0);
            }
        }
    }

    const int orow0 = blk * 64 + wave * 16 + lsub * 4;
    float* out0 = out;
    float* out1 = out + (size_t)B_DIM * A_DIM;
    #pragma unroll
    for (int c = 0; c < 8; ++c) {
        int   nn  = c * 16 + lcol;
        float bvv = bias[nn];
        float* ob = (nn & 1) ? out1 : out0;
        #pragma unroll
        for (int j = 0; j < 4; ++j) {
            float x = acc[c][j] + bvv;
            float e = __expf(2.0f * x);
            ob[(size_t)(orow0 + j) * A_DIM + (nn >> 1)] = 1.0f - 2.0f / (e + 1.0f);
        }
    }
}

extern "C" void kernel_launch(void* const* d_in, const int* in_sizes, int n_in,
                              void* d_out, int out_size, void* d_ws, size_t ws_size,
                              hipStream_t stream) {
    const float* F    = (const float*)d_in[0];  // [32768, 1024] f32
    const float* W    = (const float*)d_in[1];  // [64, 2, 1024] f32
    const float* bias = (const float*)d_in[2];  // [64, 2] f32
    float* outp       = (float*)d_out;          // [2][32768, 64] f32

    const size_t ws_needed = (size_t)N_COLS * L_DIM * sizeof(__bf16);  // 256 KB

    if (ws_size >= ws_needed) {
        bf16x8* wf = (bf16x8*)d_ws;
        hipLaunchKernelGGL(convert_w_kernel, dim3(64), dim3(256), 0, stream, W, wf);
        hipLaunchKernelGGL(branched_policy_kernel, dim3(NBLK), dim3(512), 0, stream,
                           F, wf, bias, outp);
    } else {
        hipLaunchKernelGGL(fallback_kernel, dim3(B_DIM / 64), dim3(256), 0, stream,
                           F, W, bias, outp);
    }
}